// Round 3
// baseline (428.266 us; speedup 1.0000x reference)
//
#include <hip/hip_runtime.h>
#include <hip/hip_bf16.h>

// ---------- types ----------
typedef unsigned short u16;
typedef unsigned int u32;
typedef float f32x4 __attribute__((ext_vector_type(4)));
typedef _Float16 f16x8 __attribute__((ext_vector_type(8)));
typedef u32 u32x4 __attribute__((ext_vector_type(4)));
typedef u32 u32x2 __attribute__((ext_vector_type(2)));

#define SEQ 2048
#define EDIM 1024

__device__ __forceinline__ u16 f2h(float f) {
  _Float16 h = (_Float16)f;
  return __builtin_bit_cast(u16, h);
}
__device__ __forceinline__ float h2f(u16 u) {
  return (float)__builtin_bit_cast(_Float16, u);
}
__device__ __forceinline__ u32 pk(float a, float b) {
  return (u32)f2h(a) | ((u32)f2h(b) << 16);
}

// ---------- fp32 -> fp16 convert, 8 elems/thread ----------
__global__ __launch_bounds__(256) void cvt_f16(const float* __restrict__ in,
                                               u16* __restrict__ out, int n8) {
  int i = blockIdx.x * 256 + threadIdx.x;
  if (i >= n8) return;
  const f32x4* p = (const f32x4*)(in + (size_t)i * 8);
  f32x4 a = p[0], b = p[1];
  u32x4 o = {pk(a[0], a[1]), pk(a[2], a[3]), pk(b[0], b[1]), pk(b[2], b[3])};
  *(u32x4*)(out + (size_t)i * 8) = o;
}

struct GemmP {
  const u16* A; const u16* B;
  int lda, ldb, K;
  long bsA, bsB, bsC;       // per-blockIdx.z element strides
  float* Cf; int ldc;       // EPI 0 (f32 store), EPI 3
  u16* Cb;                  // EPI 2 (f16 store)
  const float* bias;        // EPI 2,3
  const u16* resid;         // EPI 3 (h, f16, ld 512)
  u16* qk; u16* vT;         // EPI 1 (proj split)
  float scale;              // EPI 1
};

// =======================================================================
// 256x256 tile, BK=32 k-slice pipeline (depth 3), 8 waves (2Mx4N).
// m201-style fine phases: per slice 2 phases, each
//   {ds_reads -> 1 half-stage -> [counted vmcnt] -> barrier -> lgkmcnt(0)
//    -> sched_barrier -> setprio(1) 16xMFMA setprio(0) -> barrier}.
// LDS: 4 slots x (A 16KB + B 16KB) = 128KB. Swizzle identical to round 2.
// =======================================================================
template <int EPI>
__global__ __launch_bounds__(512, 2) void gemm256(GemmP p) {
  __shared__ __align__(16) char lds[131072];
  const int tid = threadIdx.x;
  const int lane = tid & 63;
  const int wave = tid >> 6;
  const int wm = wave >> 2, wn = wave & 3;     // 2 x 4 waves
  const int bn0 = blockIdx.x * 256;
  const int bm0 = blockIdx.y * 256;
  const int z = blockIdx.z;
  const u16* Ab = p.A + (long)z * p.bsA + (long)bm0 * p.lda;
  const u16* Bb = p.B + (long)z * p.bsB + (long)bn0 * p.ldb;

  // staging: per slice, A = 256 rows x 4 slots(16B) = 1024 chunks; same for B.
  const int ch0 = tid, ch1 = tid + 512;
  const int r0 = ch0 >> 2, s0 = ch0 & 3;
  const int r1 = ch1 >> 2, s1 = ch1 & 3;
  const long srcA0 = (long)r0 * p.lda + ((s0 ^ ((r0 >> 1) & 3)) << 3);
  const long srcA1 = (long)r1 * p.lda + ((s1 ^ ((r1 >> 1) & 3)) << 3);
  const long srcB0 = (long)r0 * p.ldb + ((s0 ^ ((r0 >> 1) & 3)) << 3);
  const long srcB1 = (long)r1 * p.ldb + ((s1 ^ ((r1 >> 1) & 3)) << 3);

  auto stageA = [&](int s) {
    const int base = (s & 3) * 32768;
    const int k0 = s * 32;
    __builtin_amdgcn_global_load_lds(
        (const __attribute__((address_space(1))) u32*)(Ab + k0 + srcA0),
        (__attribute__((address_space(3))) u32*)(lds + base + ch0 * 16), 16, 0, 0);
    __builtin_amdgcn_global_load_lds(
        (const __attribute__((address_space(1))) u32*)(Ab + k0 + srcA1),
        (__attribute__((address_space(3))) u32*)(lds + base + ch1 * 16), 16, 0, 0);
  };
  auto stageB = [&](int s) {
    const int base = (s & 3) * 32768;
    const int k0 = s * 32;
    __builtin_amdgcn_global_load_lds(
        (const __attribute__((address_space(1))) u32*)(Bb + k0 + srcB0),
        (__attribute__((address_space(3))) u32*)(lds + base + 16384 + ch0 * 16), 16, 0, 0);
    __builtin_amdgcn_global_load_lds(
        (const __attribute__((address_space(1))) u32*)(Bb + k0 + srcB1),
        (__attribute__((address_space(3))) u32*)(lds + base + 16384 + ch1 * 16), 16, 0, 0);
  };

  // ds_read offsets (constant across slices; only slot base changes)
  int aoff[8], boff[4];
#pragma unroll
  for (int m = 0; m < 8; ++m) {
    int r = wm * 128 + m * 16 + (lane & 15);
    aoff[m] = r * 64 + ((((lane >> 4)) ^ ((r >> 1) & 3)) << 4);
  }
#pragma unroll
  for (int n = 0; n < 4; ++n) {
    int r = wn * 64 + n * 16 + (lane & 15);
    boff[n] = 16384 + r * 64 + ((((lane >> 4)) ^ ((r >> 1) & 3)) << 4);
  }

  f32x4 acc[8][4] = {};

  // prologue: stage slices 0..2, wait for slice 0 (leave 8 loads in flight)
  stageA(0); stageB(0); stageA(1); stageB(1); stageA(2); stageB(2);
  asm volatile("s_waitcnt vmcnt(8)" ::: "memory");
  __builtin_amdgcn_s_barrier();
  asm volatile("" ::: "memory");

  const int NS = p.K >> 5;
  for (int s = 0; s < NS; ++s) {
    const char* base = lds + (s & 3) * 32768;

    // ---------------- phase 0: av0-3 + bv0-3, MFMA m0-3 ----------------
    f16x8 av0 = *(const f16x8*)(base + aoff[0]);
    f16x8 av1 = *(const f16x8*)(base + aoff[1]);
    f16x8 av2 = *(const f16x8*)(base + aoff[2]);
    f16x8 av3 = *(const f16x8*)(base + aoff[3]);
    f16x8 bv0 = *(const f16x8*)(base + boff[0]);
    f16x8 bv1 = *(const f16x8*)(base + boff[1]);
    f16x8 bv2 = *(const f16x8*)(base + boff[2]);
    f16x8 bv3 = *(const f16x8*)(base + boff[3]);
    if (s + 3 < NS) stageA(s + 3);
    asm volatile("" ::: "memory");
    __builtin_amdgcn_s_barrier();
    asm volatile("s_waitcnt lgkmcnt(0)" ::: "memory");
    __builtin_amdgcn_sched_barrier(0);
    __builtin_amdgcn_s_setprio(1);
    acc[0][0] = __builtin_amdgcn_mfma_f32_16x16x32_f16(av0, bv0, acc[0][0], 0, 0, 0);
    acc[0][1] = __builtin_amdgcn_mfma_f32_16x16x32_f16(av0, bv1, acc[0][1], 0, 0, 0);
    acc[0][2] = __builtin_amdgcn_mfma_f32_16x16x32_f16(av0, bv2, acc[0][2], 0, 0, 0);
    acc[0][3] = __builtin_amdgcn_mfma_f32_16x16x32_f16(av0, bv3, acc[0][3], 0, 0, 0);
    acc[1][0] = __builtin_amdgcn_mfma_f32_16x16x32_f16(av1, bv0, acc[1][0], 0, 0, 0);
    acc[1][1] = __builtin_amdgcn_mfma_f32_16x16x32_f16(av1, bv1, acc[1][1], 0, 0, 0);
    acc[1][2] = __builtin_amdgcn_mfma_f32_16x16x32_f16(av1, bv2, acc[1][2], 0, 0, 0);
    acc[1][3] = __builtin_amdgcn_mfma_f32_16x16x32_f16(av1, bv3, acc[1][3], 0, 0, 0);
    acc[2][0] = __builtin_amdgcn_mfma_f32_16x16x32_f16(av2, bv0, acc[2][0], 0, 0, 0);
    acc[2][1] = __builtin_amdgcn_mfma_f32_16x16x32_f16(av2, bv1, acc[2][1], 0, 0, 0);
    acc[2][2] = __builtin_amdgcn_mfma_f32_16x16x32_f16(av2, bv2, acc[2][2], 0, 0, 0);
    acc[2][3] = __builtin_amdgcn_mfma_f32_16x16x32_f16(av2, bv3, acc[2][3], 0, 0, 0);
    acc[3][0] = __builtin_amdgcn_mfma_f32_16x16x32_f16(av3, bv0, acc[3][0], 0, 0, 0);
    acc[3][1] = __builtin_amdgcn_mfma_f32_16x16x32_f16(av3, bv1, acc[3][1], 0, 0, 0);
    acc[3][2] = __builtin_amdgcn_mfma_f32_16x16x32_f16(av3, bv2, acc[3][2], 0, 0, 0);
    acc[3][3] = __builtin_amdgcn_mfma_f32_16x16x32_f16(av3, bv3, acc[3][3], 0, 0, 0);
    __builtin_amdgcn_s_setprio(0);
    asm volatile("" ::: "memory");
    __builtin_amdgcn_s_barrier();

    // ---------------- phase 1: av4-7, MFMA m4-7 (bv in regs) -----------
    f16x8 av4 = *(const f16x8*)(base + aoff[4]);
    f16x8 av5 = *(const f16x8*)(base + aoff[5]);
    f16x8 av6 = *(const f16x8*)(base + aoff[6]);
    f16x8 av7 = *(const f16x8*)(base + aoff[7]);
    if (s + 3 < NS) stageB(s + 3);
    // counted wait: guarantee slice s+1 (A and B) landed before next slice
    if (s + 3 < NS) {
      asm volatile("s_waitcnt vmcnt(8)" ::: "memory");
    } else if (s + 2 < NS) {
      asm volatile("s_waitcnt vmcnt(4)" ::: "memory");
    } else if (s + 1 < NS) {
      asm volatile("s_waitcnt vmcnt(0)" ::: "memory");
    }
    __builtin_amdgcn_s_barrier();
    asm volatile("s_waitcnt lgkmcnt(0)" ::: "memory");
    __builtin_amdgcn_sched_barrier(0);
    __builtin_amdgcn_s_setprio(1);
    acc[4][0] = __builtin_amdgcn_mfma_f32_16x16x32_f16(av4, bv0, acc[4][0], 0, 0, 0);
    acc[4][1] = __builtin_amdgcn_mfma_f32_16x16x32_f16(av4, bv1, acc[4][1], 0, 0, 0);
    acc[4][2] = __builtin_amdgcn_mfma_f32_16x16x32_f16(av4, bv2, acc[4][2], 0, 0, 0);
    acc[4][3] = __builtin_amdgcn_mfma_f32_16x16x32_f16(av4, bv3, acc[4][3], 0, 0, 0);
    acc[5][0] = __builtin_amdgcn_mfma_f32_16x16x32_f16(av5, bv0, acc[5][0], 0, 0, 0);
    acc[5][1] = __builtin_amdgcn_mfma_f32_16x16x32_f16(av5, bv1, acc[5][1], 0, 0, 0);
    acc[5][2] = __builtin_amdgcn_mfma_f32_16x16x32_f16(av5, bv2, acc[5][2], 0, 0, 0);
    acc[5][3] = __builtin_amdgcn_mfma_f32_16x16x32_f16(av5, bv3, acc[5][3], 0, 0, 0);
    acc[6][0] = __builtin_amdgcn_mfma_f32_16x16x32_f16(av6, bv0, acc[6][0], 0, 0, 0);
    acc[6][1] = __builtin_amdgcn_mfma_f32_16x16x32_f16(av6, bv1, acc[6][1], 0, 0, 0);
    acc[6][2] = __builtin_amdgcn_mfma_f32_16x16x32_f16(av6, bv2, acc[6][2], 0, 0, 0);
    acc[6][3] = __builtin_amdgcn_mfma_f32_16x16x32_f16(av6, bv3, acc[6][3], 0, 0, 0);
    acc[7][0] = __builtin_amdgcn_mfma_f32_16x16x32_f16(av7, bv0, acc[7][0], 0, 0, 0);
    acc[7][1] = __builtin_amdgcn_mfma_f32_16x16x32_f16(av7, bv1, acc[7][1], 0, 0, 0);
    acc[7][2] = __builtin_amdgcn_mfma_f32_16x16x32_f16(av7, bv2, acc[7][2], 0, 0, 0);
    acc[7][3] = __builtin_amdgcn_mfma_f32_16x16x32_f16(av7, bv3, acc[7][3], 0, 0, 0);
    __builtin_amdgcn_s_setprio(0);
    asm volatile("" ::: "memory");
    __builtin_amdgcn_s_barrier();
  }

  // epilogue: C row = (lane>>4)*4+reg, col = lane&15
#pragma unroll
  for (int i = 0; i < 8; ++i) {
#pragma unroll
    for (int j = 0; j < 4; ++j) {
      int mb = bm0 + wm * 128 + i * 16 + ((lane >> 4) << 2);
      int n = bn0 + wn * 64 + j * 16 + (lane & 15);
      if constexpr (EPI == 0) {  // plain f32 (scores)
        float* dst = p.Cf + (long)z * p.bsC + (long)mb * p.ldc + n;
#pragma unroll
        for (int r = 0; r < 4; ++r) dst[(long)r * p.ldc] = acc[i][j][r];
      } else if constexpr (EPI == 1) {  // proj split into q*SCALE | k | vT
        int b = mb >> 11, l0 = mb & 2047;
        if (n < EDIM) {
          u16* dst = p.qk + (long)b * 4194304 + (long)l0 * 1024 + n;
#pragma unroll
          for (int r = 0; r < 4; ++r) dst[r * 1024] = f2h(acc[i][j][r] * p.scale);
        } else if (n < 2 * EDIM) {
          u16* dst = p.qk + (long)b * 4194304 + 2097152 + (long)l0 * 1024 + (n - EDIM);
#pragma unroll
          for (int r = 0; r < 4; ++r) dst[r * 1024] = f2h(acc[i][j][r]);
        } else {  // vT[b][n-2048][l0..l0+3]
          u16* dst = p.vT + (long)b * 1048576 + (long)(n - 2 * EDIM) * 2048 + l0;
          u32x2 w = {pk(acc[i][j][0], acc[i][j][1]), pk(acc[i][j][2], acc[i][j][3])};
          *(u32x2*)dst = w;
        }
      } else if constexpr (EPI == 2) {  // +bias, relu, f16 out (ff1)
        u16* dst = p.Cb + (long)mb * p.ldc + n;
        float bias = p.bias[n];
#pragma unroll
        for (int r = 0; r < 4; ++r) dst[(long)r * p.ldc] = f2h(fmaxf(acc[i][j][r] + bias, 0.f));
      }
    }
  }
}

// =======================================================================
// 128x128 tile 2-barrier kernel (round-1, proven) — used for PV / ff2
// where N=512 would under-occupy 256^2 tiles.
// =======================================================================
template <int EPI>
__global__ __launch_bounds__(256) void gemm_bt(GemmP p) {
  __shared__ __align__(16) char lds[32768];  // A: [0,16K)  B: [16K,32K)
  const int tid = threadIdx.x;
  const int lane = tid & 63;
  const int wave = tid >> 6;
  const int wm = wave >> 1, wn = wave & 1;
  const int bn0 = blockIdx.x * 128;
  const int bm0 = blockIdx.y * 128;
  const int z = blockIdx.z;
  const u16* Ab = p.A + (long)z * p.bsA + (long)bm0 * p.lda;
  const u16* Bb = p.B + (long)z * p.bsB + (long)bn0 * p.ldb;

  auto stage = [&](int k0) {
#pragma unroll
    for (int i = 0; i < 4; ++i) {
      int ch = i * 256 + tid;
      int row = ch >> 3, s = ch & 7;
      int ks = ((s ^ (row & 7)) << 3);
      __builtin_amdgcn_global_load_lds(
          (const __attribute__((address_space(1))) u32*)(Ab + (long)row * p.lda + k0 + ks),
          (__attribute__((address_space(3))) u32*)(lds + ch * 16), 16, 0, 0);
    }
#pragma unroll
    for (int i = 0; i < 4; ++i) {
      int ch = i * 256 + tid;
      int row = ch >> 3, s = ch & 7;
      int ks = ((s ^ (row & 7)) << 3);
      __builtin_amdgcn_global_load_lds(
          (const __attribute__((address_space(1))) u32*)(Bb + (long)row * p.ldb + k0 + ks),
          (__attribute__((address_space(3))) u32*)(lds + 16384 + ch * 16), 16, 0, 0);
    }
  };

  f32x4 acc[4][4] = {};
  stage(0);
  const int nk = p.K >> 6;
  for (int kt = 0; kt < nk; ++kt) {
    __syncthreads();
#pragma unroll
    for (int h = 0; h < 2; ++h) {
      f16x8 av[4], bv[4];
#pragma unroll
      for (int i = 0; i < 4; ++i) {
        int row = wm * 64 + i * 16 + (lane & 15);
        int sw = ((h << 2) | (lane >> 4)) ^ (lane & 7);
        av[i] = *(const f16x8*)(lds + row * 128 + sw * 16);
      }
#pragma unroll
      for (int j = 0; j < 4; ++j) {
        int row = wn * 64 + j * 16 + (lane & 15);
        int sw = ((h << 2) | (lane >> 4)) ^ (lane & 7);
        bv[j] = *(const f16x8*)(lds + 16384 + row * 128 + sw * 16);
      }
#pragma unroll
      for (int i = 0; i < 4; ++i)
#pragma unroll
        for (int j = 0; j < 4; ++j)
          acc[i][j] = __builtin_amdgcn_mfma_f32_16x16x32_f16(av[i], bv[j], acc[i][j], 0, 0, 0);
    }
    __syncthreads();
    if (kt + 1 < nk) stage((kt + 1) << 6);
  }

#pragma unroll
  for (int i = 0; i < 4; ++i) {
#pragma unroll
    for (int j = 0; j < 4; ++j) {
      int mb = bm0 + wm * 64 + i * 16 + ((lane >> 4) << 2);
      int n = bn0 + wn * 64 + j * 16 + (lane & 15);
      if constexpr (EPI == 0) {  // plain f32 (PV)
        float* dst = p.Cf + (long)z * p.bsC + (long)mb * p.ldc + n;
#pragma unroll
        for (int r = 0; r < 4; ++r) dst[(long)r * p.ldc] = acc[i][j][r];
      } else {  // EPI 3: +bias +resid, f32 out (ff2), ld 512
        float bias = p.bias[n];
        float* dst = p.Cf + (long)mb * 512 + n;
        const u16* rs = p.resid + (long)mb * 512 + n;
#pragma unroll
        for (int r = 0; r < 4; ++r) dst[r * 512] = acc[i][j][r] + bias + h2f(rs[r * 512]);
      }
    }
  }
}

// ---------- row softmax: 1 block / row of 2048 f32 -> f16 weights ----------
__global__ __launch_bounds__(256) void softmax_rows(const float* __restrict__ S,
                                                    u16* __restrict__ W, int b0) {
  int r = blockIdx.x;
  int z = r >> 11, l = r & 2047;
  int tid = threadIdx.x, lane = tid & 63, wv = tid >> 6;
  const float* x = S + (long)r * 2048 + tid * 8;
  f32x4 a = *(const f32x4*)x, b = *(const f32x4*)(x + 4);
  float m = fmaxf(fmaxf(fmaxf(a[0], a[1]), fmaxf(a[2], a[3])),
                  fmaxf(fmaxf(b[0], b[1]), fmaxf(b[2], b[3])));
#pragma unroll
  for (int off = 32; off; off >>= 1) m = fmaxf(m, __shfl_xor(m, off));
  __shared__ float red[8];
  if (lane == 0) red[wv] = m;
  __syncthreads();
  m = fmaxf(fmaxf(red[0], red[1]), fmaxf(red[2], red[3]));
  float e[8];
  float s = 0.f;
#pragma unroll
  for (int q = 0; q < 4; ++q) { e[q] = __expf(a[q] - m); s += e[q]; }
#pragma unroll
  for (int q = 0; q < 4; ++q) { e[4 + q] = __expf(b[q] - m); s += e[4 + q]; }
#pragma unroll
  for (int off = 32; off; off >>= 1) s += __shfl_xor(s, off);
  if (lane == 0) red[4 + wv] = s;
  __syncthreads();
  s = red[4] + red[5] + red[6] + red[7];
  float inv = 1.f / s;
  u32x4 o = {pk(e[0] * inv, e[1] * inv), pk(e[2] * inv, e[3] * inv),
             pk(e[4] * inv, e[5] * inv), pk(e[6] * inv, e[7] * inv)};
  *(u32x4*)(W + (long)(b0 + z) * 4194304 + (long)l * 2048 + tid * 8) = o;
}

// ---------- LayerNorm over 512, wave per row ----------
template <int OUTF16>
__global__ __launch_bounds__(256) void ln_rows(const float* __restrict__ X,
                                               const float* __restrict__ g,
                                               const float* __restrict__ bb,
                                               void* __restrict__ out) {
  int row = blockIdx.x * 4 + (threadIdx.x >> 6);
  int lane = threadIdx.x & 63;
  const float* x = X + (long)row * 512 + lane * 8;
  f32x4 a = *(const f32x4*)x, b = *(const f32x4*)(x + 4);
  float s = a[0] + a[1] + a[2] + a[3] + b[0] + b[1] + b[2] + b[3];
  float sq = a[0] * a[0] + a[1] * a[1] + a[2] * a[2] + a[3] * a[3] +
             b[0] * b[0] + b[1] * b[1] + b[2] * b[2] + b[3] * b[3];
#pragma unroll
  for (int off = 32; off; off >>= 1) {
    s += __shfl_xor(s, off);
    sq += __shfl_xor(sq, off);
  }
  float mean = s * (1.f / 512.f);
  float var = sq * (1.f / 512.f) - mean * mean;
  float rstd = rsqrtf(var + 1e-5f);
  f32x4 g0 = *(const f32x4*)(g + lane * 8), g1v = *(const f32x4*)(g + lane * 8 + 4);
  f32x4 b0 = *(const f32x4*)(bb + lane * 8), b1v = *(const f32x4*)(bb + lane * 8 + 4);
  float o[8];
#pragma unroll
  for (int q = 0; q < 4; ++q) o[q] = (a[q] - mean) * rstd * g0[q] + b0[q];
#pragma unroll
  for (int q = 0; q < 4; ++q) o[4 + q] = (b[q] - mean) * rstd * g1v[q] + b1v[q];
  if constexpr (OUTF16) {
    u32x4 pkd = {pk(o[0], o[1]), pk(o[2], o[3]), pk(o[4], o[5]), pk(o[6], o[7])};
    *(u32x4*)((u16*)out + (long)row * 512 + lane * 8) = pkd;
  } else {
    float* dst = (float*)out + (long)row * 512 + lane * 8;
    *(f32x4*)dst = (f32x4){o[0], o[1], o[2], o[3]};
    *(f32x4*)(dst + 4) = (f32x4){o[4], o[5], o[6], o[7]};
  }
}

// ---------- launch ----------
extern "C" void kernel_launch(void* const* d_in, const int* in_sizes, int n_in,
                              void* d_out, int out_size, void* d_ws, size_t ws_size,
                              hipStream_t stream) {
  const float* x = (const float*)d_in[0];
  const float* wp = (const float*)d_in[1];
  const float* w1 = (const float*)d_in[2];
  const float* b1 = (const float*)d_in[3];
  const float* w2 = (const float*)d_in[4];
  const float* b2 = (const float*)d_in[5];
  const float* g1 = (const float*)d_in[6];
  const float* be1 = (const float*)d_in[7];
  const float* g2 = (const float*)d_in[8];
  const float* be2 = (const float*)d_in[9];

  char* ws = (char*)d_ws;
  size_t off = 0;
  auto alloc = [&](size_t bytes) {
    char* p = ws + off;
    off += (bytes + 255) & ~(size_t)255;
    return p;
  };
  u16* wpb = (u16*)alloc(2560 * 1024 * 2);
  u16* w1b = (u16*)alloc(2048 * 512 * 2);
  u16* w2b = (u16*)alloc(512 * 2048 * 2);
  char* xb_region = alloc(33554432);   // x f16 -> attn_out f32
  u16* qk = (u16*)alloc(67108864);     // [q|k] f16 -> attnw -> ff1
  u16* vT = (u16*)alloc(16777216);     // v transposed (B,512,2048) f16
  u16* hb = (u16*)alloc(16777216);     // h f16
  size_t remain = (ws_size > off) ? ws_size - off : 0;
  int bpl = (remain >= (size_t)67108864 + 256) ? 4 : 2;
  char* sc_region = alloc((size_t)bpl * 2048 * 2048 * 4);
  if (off > ws_size) return;

  u16* xb = (u16*)xb_region;
  float* attn_f = (float*)xb_region;
  float* scores = (float*)sc_region;
  float* y32 = (float*)sc_region;
  u16* ff1 = qk;

  const float SC = (float)(0.03125 * 2.0 * 7.6246189861593985);

  cvt_f16<<<dim3(8192), dim3(256), 0, stream>>>(x, xb, 2097152);
  cvt_f16<<<dim3(1280), dim3(256), 0, stream>>>(wp, wpb, 327680);
  cvt_f16<<<dim3(512), dim3(256), 0, stream>>>(w1, w1b, 131072);
  cvt_f16<<<dim3(512), dim3(256), 0, stream>>>(w2, w2b, 131072);

  {  // proj: (16384x1024) @ (2560x1024)^T, split epilogue
    GemmP p{};
    p.A = xb; p.lda = 1024; p.B = wpb; p.ldb = 1024; p.K = 1024;
    p.qk = qk; p.vT = vT; p.scale = SC;
    gemm256<1><<<dim3(10, 64, 1), 512, 0, stream>>>(p);
  }

  for (int it = 0; it < 8 / bpl; ++it) {  // scores + softmax
    int b0 = it * bpl;
    GemmP p{};
    p.A = qk + (long)b0 * 4194304; p.lda = 1024; p.bsA = 4194304;
    p.B = qk + (long)b0 * 4194304 + 2097152; p.ldb = 1024; p.bsB = 4194304;
    p.K = 1024; p.Cf = scores; p.ldc = 2048; p.bsC = 4194304;
    gemm256<0><<<dim3(8, 8, bpl), 512, 0, stream>>>(p);
    softmax_rows<<<dim3(bpl * 2048), dim3(256), 0, stream>>>(scores, qk, b0);
  }

  {  // PV: attnw(2048x2048) @ vT(512x2048)^T per batch  (128^2 kernel)
    GemmP p{};
    p.A = qk; p.lda = 2048; p.bsA = 4194304;
    p.B = vT; p.ldb = 2048; p.bsB = 1048576;
    p.K = 2048; p.Cf = attn_f; p.ldc = 512; p.bsC = 1048576;
    gemm_bt<0><<<dim3(4, 16, 8), 256, 0, stream>>>(p);
  }

  ln_rows<1><<<dim3(4096), dim3(256), 0, stream>>>(attn_f, g1, be1, hb);

  {  // ff1: h(16384x512) @ w1(2048x512)^T, +b1 relu -> f16
    GemmP p{};
    p.A = hb; p.lda = 512; p.B = w1b; p.ldb = 512; p.K = 512;
    p.Cb = ff1; p.ldc = 2048; p.bias = b1;
    gemm256<2><<<dim3(8, 64, 1), 512, 0, stream>>>(p);
  }

  {  // ff2: ff1(16384x2048) @ w2(512x2048)^T, +b2 +h -> f32  (128^2 kernel)
    GemmP p{};
    p.A = ff1; p.lda = 2048; p.B = w2b; p.ldb = 2048; p.K = 2048;
    p.Cf = y32; p.bias = b2; p.resid = hb;
    gemm_bt<3><<<dim3(4, 128, 1), 256, 0, stream>>>(p);
  }

  ln_rows<0><<<dim3(4096), dim3(256), 0, stream>>>(y32, g2, be2, (float*)d_out);
}

// Round 4
// 417.771 us; speedup vs baseline: 1.0251x; 1.0251x over previous
//
#include <hip/hip_runtime.h>
#include <hip/hip_bf16.h>

// ---------- types ----------
typedef unsigned short u16;
typedef unsigned int u32;
typedef float f32x4 __attribute__((ext_vector_type(4)));
typedef _Float16 f16x8 __attribute__((ext_vector_type(8)));
typedef u32 u32x4 __attribute__((ext_vector_type(4)));
typedef u32 u32x2 __attribute__((ext_vector_type(2)));

#define SEQ 2048
#define EDIM 1024

__device__ __forceinline__ u16 f2h(float f) {
  _Float16 h = (_Float16)f;
  return __builtin_bit_cast(u16, h);
}
__device__ __forceinline__ float h2f(u16 u) {
  return (float)__builtin_bit_cast(_Float16, u);
}
__device__ __forceinline__ u32 pk(float a, float b) {
  return (u32)f2h(a) | ((u32)f2h(b) << 16);
}

// ---------- fp32 -> fp16 convert, 8 elems/thread ----------
__global__ __launch_bounds__(256) void cvt_f16(const float* __restrict__ in,
                                               u16* __restrict__ out, int n8) {
  int i = blockIdx.x * 256 + threadIdx.x;
  if (i >= n8) return;
  const f32x4* p = (const f32x4*)(in + (size_t)i * 8);
  f32x4 a = p[0], b = p[1];
  u32x4 o = {pk(a[0], a[1]), pk(a[2], a[3]), pk(b[0], b[1]), pk(b[2], b[3])};
  *(u32x4*)(out + (size_t)i * 8) = o;
}

struct GemmP {
  const u16* A; const u16* B;
  int lda, ldb, K;
  long bsA, bsB, bsC;       // per-blockIdx.z element strides
  float* Cf;                // EPI 3 (f32 store)
  int ldc;
  u16* Cb;                  // EPI 2/4 (f16 store)
  const float* bias;        // EPI 2,3
  const u16* resid;         // EPI 3 (h, f16, ld 512)
  u16* qk; u16* vT;         // EPI 1 (proj split)
  float scale;              // EPI 1
};

// =======================================================================
// 128x128 tile, BK=64, 4 waves (2x2), 16x16x32 f16 MFMA, 2-barrier loop.
// All global chunk pointers and LDS fragment offsets precomputed once;
// staging advances 8 pointers by 64 elems/step (VALU diet vs round 1).
// EPI: 1 = proj split (q*SC | k | vT), 2 = +bias relu f16 (ff1),
//      3 = +bias +resid f32 (ff2), 4 = plain f16 (scores, PV).
// =======================================================================
template <int EPI>
__global__ __launch_bounds__(256) void gemm_bt(GemmP p) {
  __shared__ __align__(16) char lds[32768];  // A: [0,16K)  B: [16K,32K)
  const int tid = threadIdx.x;
  const int lane = tid & 63;
  const int wave = tid >> 6;
  const int wm = wave >> 1, wn = wave & 1;
  const int bn0 = blockIdx.x * 128;
  const int bm0 = blockIdx.y * 128;
  const int z = blockIdx.z;

  // --- precompute staging state: 4 A-chunks + 4 B-chunks per thread ---
  const u16* gA[4]; const u16* gB[4];
  int ldsA[4], ldsB[4];
  {
    const u16* Ab = p.A + (long)z * p.bsA + (long)bm0 * p.lda;
    const u16* Bb = p.B + (long)z * p.bsB + (long)bn0 * p.ldb;
#pragma unroll
    for (int i = 0; i < 4; ++i) {
      int ch = i * 256 + tid;
      int row = ch >> 3, s = ch & 7;
      int ks = ((s ^ (row & 7)) << 3);  // inverse-swizzled global source
      gA[i] = Ab + (long)row * p.lda + ks;
      gB[i] = Bb + (long)row * p.ldb + ks;
      ldsA[i] = ch * 16;
      ldsB[i] = 16384 + ch * 16;
    }
  }
  auto stage = [&]() {
#pragma unroll
    for (int i = 0; i < 4; ++i) {
      __builtin_amdgcn_global_load_lds(
          (const __attribute__((address_space(1))) u32*)gA[i],
          (__attribute__((address_space(3))) u32*)(lds + ldsA[i]), 16, 0, 0);
      gA[i] += 64;
    }
#pragma unroll
    for (int i = 0; i < 4; ++i) {
      __builtin_amdgcn_global_load_lds(
          (const __attribute__((address_space(1))) u32*)gB[i],
          (__attribute__((address_space(3))) u32*)(lds + ldsB[i]), 16, 0, 0);
      gB[i] += 64;
    }
  };

  // --- precompute LDS fragment read offsets (2 K-halves x 4 frags) ---
  int ao[2][4], bo[2][4];
#pragma unroll
  for (int h = 0; h < 2; ++h) {
#pragma unroll
    for (int i = 0; i < 4; ++i) {
      int rA = wm * 64 + i * 16 + (lane & 15);
      ao[h][i] = rA * 128 + ((((h << 2) | (lane >> 4)) ^ (rA & 7)) << 4);
      int rB = wn * 64 + i * 16 + (lane & 15);
      bo[h][i] = 16384 + rB * 128 + ((((h << 2) | (lane >> 4)) ^ (rB & 7)) << 4);
    }
  }

  f32x4 acc[4][4] = {};
  stage();
  const int nk = p.K >> 6;
  for (int kt = 0; kt < nk; ++kt) {
    __syncthreads();  // staging visible (compiler drains vmcnt before barrier)
#pragma unroll
    for (int h = 0; h < 2; ++h) {
      f16x8 av[4], bv[4];
#pragma unroll
      for (int i = 0; i < 4; ++i) av[i] = *(const f16x8*)(lds + ao[h][i]);
#pragma unroll
      for (int j = 0; j < 4; ++j) bv[j] = *(const f16x8*)(lds + bo[h][j]);
#pragma unroll
      for (int i = 0; i < 4; ++i)
#pragma unroll
        for (int j = 0; j < 4; ++j)
          acc[i][j] = __builtin_amdgcn_mfma_f32_16x16x32_f16(av[i], bv[j], acc[i][j], 0, 0, 0);
    }
    __syncthreads();  // all reads done before restage
    if (kt + 1 < nk) stage();
  }

  // epilogue: C row = (lane>>4)*4+reg, col = lane&15 (m89 layout)
#pragma unroll
  for (int i = 0; i < 4; ++i) {
#pragma unroll
    for (int j = 0; j < 4; ++j) {
      int mb = bm0 + wm * 64 + i * 16 + ((lane >> 4) << 2);
      int n = bn0 + wn * 64 + j * 16 + (lane & 15);
      if constexpr (EPI == 1) {  // proj split into q*SCALE | k | vT
        int b = mb >> 11, l0 = mb & 2047;
        if (n < EDIM) {
          u16* dst = p.qk + (long)b * 4194304 + (long)l0 * 1024 + n;
#pragma unroll
          for (int r = 0; r < 4; ++r) dst[r * 1024] = f2h(acc[i][j][r] * p.scale);
        } else if (n < 2 * EDIM) {
          u16* dst = p.qk + (long)b * 4194304 + 2097152 + (long)l0 * 1024 + (n - EDIM);
#pragma unroll
          for (int r = 0; r < 4; ++r) dst[r * 1024] = f2h(acc[i][j][r]);
        } else {  // vT[b][n-2048][l0..l0+3] -- 8B packed store
          u16* dst = p.vT + (long)b * 1048576 + (long)(n - 2 * EDIM) * 2048 + l0;
          u32x2 w = {pk(acc[i][j][0], acc[i][j][1]), pk(acc[i][j][2], acc[i][j][3])};
          *(u32x2*)dst = w;
        }
      } else if constexpr (EPI == 2) {  // +bias, relu, f16 out (ff1)
        u16* dst = p.Cb + (long)mb * p.ldc + n;
        float bias = p.bias[n];
#pragma unroll
        for (int r = 0; r < 4; ++r) dst[(long)r * p.ldc] = f2h(fmaxf(acc[i][j][r] + bias, 0.f));
      } else if constexpr (EPI == 3) {  // +bias +resid, f32 out (ff2), ld 512
        float bias = p.bias[n];
        float* dst = p.Cf + (long)mb * 512 + n;
        const u16* rs = p.resid + (long)mb * 512 + n;
#pragma unroll
        for (int r = 0; r < 4; ++r) dst[r * 512] = acc[i][j][r] + bias + h2f(rs[r * 512]);
      } else {  // EPI 4: plain f16 (scores, PV)
        u16* dst = p.Cb + (long)z * p.bsC + (long)mb * p.ldc + n;
#pragma unroll
        for (int r = 0; r < 4; ++r) dst[(long)r * p.ldc] = f2h(acc[i][j][r]);
      }
    }
  }
}

// ---------- row softmax: 1 block / row of 2048 f16 -> f16 weights ----------
__global__ __launch_bounds__(256) void softmax_rows(const u16* __restrict__ S,
                                                    u16* __restrict__ W, int b0) {
  int r = blockIdx.x;
  int z = r >> 11, l = r & 2047;
  int tid = threadIdx.x, lane = tid & 63, wv = tid >> 6;
  const u16* x = S + (long)r * 2048 + tid * 8;
  u32x4 raw = *(const u32x4*)x;
  float e[8];
#pragma unroll
  for (int q = 0; q < 4; ++q) {
    e[2 * q] = h2f((u16)(raw[q] & 0xffff));
    e[2 * q + 1] = h2f((u16)(raw[q] >> 16));
  }
  float m = e[0];
#pragma unroll
  for (int q = 1; q < 8; ++q) m = fmaxf(m, e[q]);
#pragma unroll
  for (int off = 32; off; off >>= 1) m = fmaxf(m, __shfl_xor(m, off));
  __shared__ float red[8];
  if (lane == 0) red[wv] = m;
  __syncthreads();
  m = fmaxf(fmaxf(red[0], red[1]), fmaxf(red[2], red[3]));
  float s = 0.f;
#pragma unroll
  for (int q = 0; q < 8; ++q) { e[q] = __expf(e[q] - m); s += e[q]; }
#pragma unroll
  for (int off = 32; off; off >>= 1) s += __shfl_xor(s, off);
  if (lane == 0) red[4 + wv] = s;
  __syncthreads();
  s = red[4] + red[5] + red[6] + red[7];
  float inv = 1.f / s;
  u32x4 o = {pk(e[0] * inv, e[1] * inv), pk(e[2] * inv, e[3] * inv),
             pk(e[4] * inv, e[5] * inv), pk(e[6] * inv, e[7] * inv)};
  *(u32x4*)(W + (long)(b0 + z) * 4194304 + (long)l * 2048 + tid * 8) = o;
}

// ---------- LayerNorm over 512, wave per row ----------
template <int INF16, int OUTF16>
__global__ __launch_bounds__(256) void ln_rows(const void* __restrict__ X,
                                               const float* __restrict__ g,
                                               const float* __restrict__ bb,
                                               void* __restrict__ out) {
  int row = blockIdx.x * 4 + (threadIdx.x >> 6);
  int lane = threadIdx.x & 63;
  float v[8];
  if constexpr (INF16) {
    u32x4 raw = *(const u32x4*)((const u16*)X + (long)row * 512 + lane * 8);
#pragma unroll
    for (int q = 0; q < 4; ++q) {
      v[2 * q] = h2f((u16)(raw[q] & 0xffff));
      v[2 * q + 1] = h2f((u16)(raw[q] >> 16));
    }
  } else {
    const float* x = (const float*)X + (long)row * 512 + lane * 8;
    f32x4 a = *(const f32x4*)x, b = *(const f32x4*)(x + 4);
#pragma unroll
    for (int q = 0; q < 4; ++q) { v[q] = a[q]; v[4 + q] = b[q]; }
  }
  float s = 0.f, sq = 0.f;
#pragma unroll
  for (int q = 0; q < 8; ++q) { s += v[q]; sq += v[q] * v[q]; }
#pragma unroll
  for (int off = 32; off; off >>= 1) {
    s += __shfl_xor(s, off);
    sq += __shfl_xor(sq, off);
  }
  float mean = s * (1.f / 512.f);
  float var = sq * (1.f / 512.f) - mean * mean;
  float rstd = rsqrtf(var + 1e-5f);
  f32x4 g0 = *(const f32x4*)(g + lane * 8), g1v = *(const f32x4*)(g + lane * 8 + 4);
  f32x4 b0 = *(const f32x4*)(bb + lane * 8), b1v = *(const f32x4*)(bb + lane * 8 + 4);
  float o[8];
#pragma unroll
  for (int q = 0; q < 4; ++q) o[q] = (v[q] - mean) * rstd * g0[q] + b0[q];
#pragma unroll
  for (int q = 0; q < 4; ++q) o[4 + q] = (v[4 + q] - mean) * rstd * g1v[q] + b1v[q];
  if constexpr (OUTF16) {
    u32x4 pkd = {pk(o[0], o[1]), pk(o[2], o[3]), pk(o[4], o[5]), pk(o[6], o[7])};
    *(u32x4*)((u16*)out + (long)row * 512 + lane * 8) = pkd;
  } else {
    float* dst = (float*)out + (long)row * 512 + lane * 8;
    *(f32x4*)dst = (f32x4){o[0], o[1], o[2], o[3]};
    *(f32x4*)(dst + 4) = (f32x4){o[4], o[5], o[6], o[7]};
  }
}

// ---------- launch ----------
extern "C" void kernel_launch(void* const* d_in, const int* in_sizes, int n_in,
                              void* d_out, int out_size, void* d_ws, size_t ws_size,
                              hipStream_t stream) {
  const float* x = (const float*)d_in[0];
  const float* wp = (const float*)d_in[1];
  const float* w1 = (const float*)d_in[2];
  const float* b1 = (const float*)d_in[3];
  const float* w2 = (const float*)d_in[4];
  const float* b2 = (const float*)d_in[5];
  const float* g1 = (const float*)d_in[6];
  const float* be1 = (const float*)d_in[7];
  const float* g2 = (const float*)d_in[8];
  const float* be2 = (const float*)d_in[9];

  char* ws = (char*)d_ws;
  size_t off = 0;
  auto alloc = [&](size_t bytes) {
    char* p = ws + off;
    off += (bytes + 255) & ~(size_t)255;
    return p;
  };
  u16* wpb = (u16*)alloc(2560 * 1024 * 2);      // in_proj f16
  u16* w1b = (u16*)alloc(2048 * 512 * 2);       // w1 f16
  u16* w2b = (u16*)alloc(512 * 2048 * 2);       // w2 f16
  char* xb_region = alloc(33554432);            // x f16 -> attn_out f16
  u16* qk = (u16*)alloc(67108864);              // [q|k] f16 -> attnw -> ff1
  u16* vT = (u16*)alloc(16777216);              // v transposed (B,512,2048) f16
  u16* hb = (u16*)alloc(16777216);              // h f16
  char* sc_region = alloc(33554432);            // scores f16 (4 batches) -> y32
  if (off > ws_size) return;  // workspace too small -> visible failure

  u16* xb = (u16*)xb_region;
  u16* attn16 = (u16*)xb_region;                // PV output f16 (x dead by then)
  u16* scores = (u16*)sc_region;                // f16 scores, 4 batches
  float* y32 = (float*)sc_region;               // ff2 f32 out (scores dead)
  u16* ff1 = qk;

  const float SC = (float)(0.03125 * 2.0 * 7.6246189861593985);  // sqrt(1/E)*2*ln(2048)

  cvt_f16<<<dim3(8192), dim3(256), 0, stream>>>(x, xb, 2097152);
  cvt_f16<<<dim3(1280), dim3(256), 0, stream>>>(wp, wpb, 327680);
  cvt_f16<<<dim3(512), dim3(256), 0, stream>>>(w1, w1b, 131072);
  cvt_f16<<<dim3(512), dim3(256), 0, stream>>>(w2, w2b, 131072);

  {  // proj: (16384x1024) @ (2560x1024)^T, split epilogue
    GemmP p{};
    p.A = xb; p.lda = 1024; p.B = wpb; p.ldb = 1024; p.K = 1024;
    p.qk = qk; p.vT = vT; p.scale = SC;
    gemm_bt<1><<<dim3(20, 128, 1), 256, 0, stream>>>(p);
  }

  for (int it = 0; it < 2; ++it) {  // scores + softmax, 4 batches at a time
    int b0 = it * 4;
    GemmP p{};
    p.A = qk + (long)b0 * 4194304; p.lda = 1024; p.bsA = 4194304;
    p.B = qk + (long)b0 * 4194304 + 2097152; p.ldb = 1024; p.bsB = 4194304;
    p.K = 1024; p.Cb = scores; p.ldc = 2048; p.bsC = 4194304;
    gemm_bt<4><<<dim3(16, 16, 4), 256, 0, stream>>>(p);
    softmax_rows<<<dim3(8192), dim3(256), 0, stream>>>(scores, qk, b0);
  }

  {  // PV: attnw(2048x2048) @ vT(512x2048)^T per batch -> f16
    GemmP p{};
    p.A = qk; p.lda = 2048; p.bsA = 4194304;
    p.B = vT; p.ldb = 2048; p.bsB = 1048576;
    p.K = 2048; p.Cb = attn16; p.ldc = 512; p.bsC = 1048576;
    gemm_bt<4><<<dim3(4, 16, 8), 256, 0, stream>>>(p);
  }

  ln_rows<1, 1><<<dim3(4096), dim3(256), 0, stream>>>(attn16, g1, be1, hb);

  {  // ff1: h(16384x512) @ w1(2048x512)^T, +b1 relu -> f16
    GemmP p{};
    p.A = hb; p.lda = 512; p.B = w1b; p.ldb = 512; p.K = 512;
    p.Cb = ff1; p.ldc = 2048; p.bias = b1;
    gemm_bt<2><<<dim3(16, 128, 1), 256, 0, stream>>>(p);
  }

  {  // ff2: ff1(16384x2048) @ w2(512x2048)^T, +b2 +h -> f32
    GemmP p{};
    p.A = ff1; p.lda = 2048; p.B = w2b; p.ldb = 2048; p.K = 2048;
    p.Cf = y32; p.bias = b2; p.resid = hb;
    gemm_bt<3><<<dim3(4, 128, 1), 256, 0, stream>>>(p);
  }

  ln_rows<0, 0><<<dim3(4096), dim3(256), 0, stream>>>(y32, g2, be2, (float*)d_out);
}

// Round 5
// 400.127 us; speedup vs baseline: 1.0703x; 1.0441x over previous
//
#include <hip/hip_runtime.h>
#include <hip/hip_bf16.h>

// ---------- types ----------
typedef unsigned short u16;
typedef unsigned int u32;
typedef float f32x4 __attribute__((ext_vector_type(4)));
typedef _Float16 f16x8 __attribute__((ext_vector_type(8)));
typedef u32 u32x4 __attribute__((ext_vector_type(4)));
typedef u32 u32x2 __attribute__((ext_vector_type(2)));

#define SEQ 2048
#define EDIM 1024

__device__ __forceinline__ u16 f2h(float f) {
  _Float16 h = (_Float16)f;
  return __builtin_bit_cast(u16, h);
}
__device__ __forceinline__ float h2f(u16 u) {
  return (float)__builtin_bit_cast(_Float16, u);
}
__device__ __forceinline__ u32 pk(float a, float b) {
  return (u32)f2h(a) | ((u32)f2h(b) << 16);
}

// ---------- fused fp32 -> fp16 convert for all 4 inputs, 8 elems/thread ----
#define N_X  2097152   // x: 16M elems /8
#define N_WP 327680    // in_proj_w
#define N_W1 131072    // w1
#define N_W2 131072    // w2
__global__ __launch_bounds__(256) void cvt_all(const float* __restrict__ x, u16* __restrict__ xb,
                                               const float* __restrict__ wp, u16* __restrict__ wpb,
                                               const float* __restrict__ w1, u16* __restrict__ w1b,
                                               const float* __restrict__ w2, u16* __restrict__ w2b) {
  int i = blockIdx.x * 256 + threadIdx.x;
  const float* src; u16* dst; int li;
  if (i < N_X) { src = x; dst = xb; li = i; }
  else if (i < N_X + N_WP) { src = wp; dst = wpb; li = i - N_X; }
  else if (i < N_X + N_WP + N_W1) { src = w1; dst = w1b; li = i - N_X - N_WP; }
  else if (i < N_X + N_WP + N_W1 + N_W2) { src = w2; dst = w2b; li = i - N_X - N_WP - N_W1; }
  else return;
  const f32x4* p = (const f32x4*)(src + (size_t)li * 8);
  f32x4 a = p[0], b = p[1];
  u32x4 o = {pk(a[0], a[1]), pk(a[2], a[3]), pk(b[0], b[1]), pk(b[2], b[3])};
  *(u32x4*)(dst + (size_t)li * 8) = o;
}

struct GemmP {
  const u16* A; const u16* B;
  int lda, ldb, K;
  long bsA, bsB, bsC;       // per-blockIdx.z element strides
  int ldc;
  u16* Cb;                  // EPI 2/3/4 (f16 store)
  const float* bias;        // EPI 2,3
  const u16* resid;         // EPI 3 (h, f16, ld 512)
  u16* qk; u16* vT;         // EPI 1 (proj split)
  float scale;              // EPI 1
};

// =======================================================================
// 128x128 tile, BK=64, 4 waves (2x2), 16x16x32 f16 MFMA, 2-barrier loop.
// Proven m97-class structure (MfmaUtil ~36%). EPI:
//   1 = proj split (q*SC | k | vT), 2 = +bias relu f16 (ff1),
//   3 = +bias +resid f16 (ff2), 4 = plain f16 (scores, PV).
// =======================================================================
template <int EPI>
__global__ __launch_bounds__(256) void gemm_bt(GemmP p) {
  __shared__ __align__(16) char lds[32768];  // A: [0,16K)  B: [16K,32K)
  const int tid = threadIdx.x;
  const int lane = tid & 63;
  const int wave = tid >> 6;
  const int wm = wave >> 1, wn = wave & 1;
  const int bn0 = blockIdx.x * 128;
  const int bm0 = blockIdx.y * 128;
  const int z = blockIdx.z;

  const u16* gA[4]; const u16* gB[4];
  int ldsA[4], ldsB[4];
  {
    const u16* Ab = p.A + (long)z * p.bsA + (long)bm0 * p.lda;
    const u16* Bb = p.B + (long)z * p.bsB + (long)bn0 * p.ldb;
#pragma unroll
    for (int i = 0; i < 4; ++i) {
      int ch = i * 256 + tid;
      int row = ch >> 3, s = ch & 7;
      int ks = ((s ^ (row & 7)) << 3);  // inverse-swizzled global source
      gA[i] = Ab + (long)row * p.lda + ks;
      gB[i] = Bb + (long)row * p.ldb + ks;
      ldsA[i] = ch * 16;
      ldsB[i] = 16384 + ch * 16;
    }
  }
  auto stage = [&]() {
#pragma unroll
    for (int i = 0; i < 4; ++i) {
      __builtin_amdgcn_global_load_lds(
          (const __attribute__((address_space(1))) u32*)gA[i],
          (__attribute__((address_space(3))) u32*)(lds + ldsA[i]), 16, 0, 0);
      gA[i] += 64;
    }
#pragma unroll
    for (int i = 0; i < 4; ++i) {
      __builtin_amdgcn_global_load_lds(
          (const __attribute__((address_space(1))) u32*)gB[i],
          (__attribute__((address_space(3))) u32*)(lds + ldsB[i]), 16, 0, 0);
      gB[i] += 64;
    }
  };

  int ao[2][4], bo[2][4];
#pragma unroll
  for (int h = 0; h < 2; ++h) {
#pragma unroll
    for (int i = 0; i < 4; ++i) {
      int rA = wm * 64 + i * 16 + (lane & 15);
      ao[h][i] = rA * 128 + ((((h << 2) | (lane >> 4)) ^ (rA & 7)) << 4);
      int rB = wn * 64 + i * 16 + (lane & 15);
      bo[h][i] = 16384 + rB * 128 + ((((h << 2) | (lane >> 4)) ^ (rB & 7)) << 4);
    }
  }

  f32x4 acc[4][4] = {};
  stage();
  const int nk = p.K >> 6;
  for (int kt = 0; kt < nk; ++kt) {
    __syncthreads();  // staging visible (compiler drains vmcnt before barrier)
#pragma unroll
    for (int h = 0; h < 2; ++h) {
      f16x8 av[4], bv[4];
#pragma unroll
      for (int i = 0; i < 4; ++i) av[i] = *(const f16x8*)(lds + ao[h][i]);
#pragma unroll
      for (int j = 0; j < 4; ++j) bv[j] = *(const f16x8*)(lds + bo[h][j]);
#pragma unroll
      for (int i = 0; i < 4; ++i)
#pragma unroll
        for (int j = 0; j < 4; ++j)
          acc[i][j] = __builtin_amdgcn_mfma_f32_16x16x32_f16(av[i], bv[j], acc[i][j], 0, 0, 0);
    }
    __syncthreads();  // all reads done before restage
    if (kt + 1 < nk) stage();
  }

  // epilogue: C row = (lane>>4)*4+reg, col = lane&15 (m89 layout)
#pragma unroll
  for (int i = 0; i < 4; ++i) {
#pragma unroll
    for (int j = 0; j < 4; ++j) {
      int mb = bm0 + wm * 64 + i * 16 + ((lane >> 4) << 2);
      int n = bn0 + wn * 64 + j * 16 + (lane & 15);
      if constexpr (EPI == 1) {  // proj split into q*SCALE | k | vT
        int b = mb >> 11, l0 = mb & 2047;
        if (n < EDIM) {
          u16* dst = p.qk + (long)b * 4194304 + (long)l0 * 1024 + n;
#pragma unroll
          for (int r = 0; r < 4; ++r) dst[r * 1024] = f2h(acc[i][j][r] * p.scale);
        } else if (n < 2 * EDIM) {
          u16* dst = p.qk + (long)b * 4194304 + 2097152 + (long)l0 * 1024 + (n - EDIM);
#pragma unroll
          for (int r = 0; r < 4; ++r) dst[r * 1024] = f2h(acc[i][j][r]);
        } else {  // vT[b][n-2048][l0..l0+3] -- 8B packed store
          u16* dst = p.vT + (long)b * 1048576 + (long)(n - 2 * EDIM) * 2048 + l0;
          u32x2 w = {pk(acc[i][j][0], acc[i][j][1]), pk(acc[i][j][2], acc[i][j][3])};
          *(u32x2*)dst = w;
        }
      } else if constexpr (EPI == 2) {  // +bias, relu, f16 out (ff1)
        u16* dst = p.Cb + (long)mb * p.ldc + n;
        float bias = p.bias[n];
#pragma unroll
        for (int r = 0; r < 4; ++r) dst[(long)r * p.ldc] = f2h(fmaxf(acc[i][j][r] + bias, 0.f));
      } else if constexpr (EPI == 3) {  // +bias +resid, f16 out (ff2), ld 512
        float bias = p.bias[n];
        u16* dst = p.Cb + (long)mb * 512 + n;
        const u16* rs = p.resid + (long)mb * 512 + n;
#pragma unroll
        for (int r = 0; r < 4; ++r) dst[r * 512] = f2h(acc[i][j][r] + bias + h2f(rs[r * 512]));
      } else {  // EPI 4: plain f16 (scores, PV)
        u16* dst = p.Cb + (long)z * p.bsC + (long)mb * p.ldc + n;
#pragma unroll
        for (int r = 0; r < 4; ++r) dst[(long)r * p.ldc] = f2h(acc[i][j][r]);
      }
    }
  }
}

// ---------- row softmax: 1 block / row of 2048 f16 -> f16 weights ----------
__global__ __launch_bounds__(256) void softmax_rows(const u16* __restrict__ S,
                                                    u16* __restrict__ W, int b0) {
  int r = blockIdx.x;
  int z = r >> 11, l = r & 2047;
  int tid = threadIdx.x, lane = tid & 63, wv = tid >> 6;
  const u16* x = S + (long)r * 2048 + tid * 8;
  u32x4 raw = *(const u32x4*)x;
  float e[8];
#pragma unroll
  for (int q = 0; q < 4; ++q) {
    e[2 * q] = h2f((u16)(raw[q] & 0xffff));
    e[2 * q + 1] = h2f((u16)(raw[q] >> 16));
  }
  float m = e[0];
#pragma unroll
  for (int q = 1; q < 8; ++q) m = fmaxf(m, e[q]);
#pragma unroll
  for (int off = 32; off; off >>= 1) m = fmaxf(m, __shfl_xor(m, off));
  __shared__ float red[8];
  if (lane == 0) red[wv] = m;
  __syncthreads();
  m = fmaxf(fmaxf(red[0], red[1]), fmaxf(red[2], red[3]));
  float s = 0.f;
#pragma unroll
  for (int q = 0; q < 8; ++q) { e[q] = __expf(e[q] - m); s += e[q]; }
#pragma unroll
  for (int off = 32; off; off >>= 1) s += __shfl_xor(s, off);
  if (lane == 0) red[4 + wv] = s;
  __syncthreads();
  s = red[4] + red[5] + red[6] + red[7];
  float inv = 1.f / s;
  u32x4 o = {pk(e[0] * inv, e[1] * inv), pk(e[2] * inv, e[3] * inv),
             pk(e[4] * inv, e[5] * inv), pk(e[6] * inv, e[7] * inv)};
  *(u32x4*)(W + (long)(b0 + z) * 4194304 + (long)l * 2048 + tid * 8) = o;
}

// ---------- LayerNorm over 512, wave per row ----------
template <int INF16, int OUTF16>
__global__ __launch_bounds__(256) void ln_rows(const void* __restrict__ X,
                                               const float* __restrict__ g,
                                               const float* __restrict__ bb,
                                               void* __restrict__ out) {
  int row = blockIdx.x * 4 + (threadIdx.x >> 6);
  int lane = threadIdx.x & 63;
  float v[8];
  if constexpr (INF16) {
    u32x4 raw = *(const u32x4*)((const u16*)X + (long)row * 512 + lane * 8);
#pragma unroll
    for (int q = 0; q < 4; ++q) {
      v[2 * q] = h2f((u16)(raw[q] & 0xffff));
      v[2 * q + 1] = h2f((u16)(raw[q] >> 16));
    }
  } else {
    const float* x = (const float*)X + (long)row * 512 + lane * 8;
    f32x4 a = *(const f32x4*)x, b = *(const f32x4*)(x + 4);
#pragma unroll
    for (int q = 0; q < 4; ++q) { v[q] = a[q]; v[4 + q] = b[q]; }
  }
  float s = 0.f, sq = 0.f;
#pragma unroll
  for (int q = 0; q < 8; ++q) { s += v[q]; sq += v[q] * v[q]; }
#pragma unroll
  for (int off = 32; off; off >>= 1) {
    s += __shfl_xor(s, off);
    sq += __shfl_xor(sq, off);
  }
  float mean = s * (1.f / 512.f);
  float var = sq * (1.f / 512.f) - mean * mean;
  float rstd = rsqrtf(var + 1e-5f);
  f32x4 g0 = *(const f32x4*)(g + lane * 8), g1v = *(const f32x4*)(g + lane * 8 + 4);
  f32x4 b0 = *(const f32x4*)(bb + lane * 8), b1v = *(const f32x4*)(bb + lane * 8 + 4);
  float o[8];
#pragma unroll
  for (int q = 0; q < 4; ++q) o[q] = (v[q] - mean) * rstd * g0[q] + b0[q];
#pragma unroll
  for (int q = 0; q < 4; ++q) o[4 + q] = (v[4 + q] - mean) * rstd * g1v[q] + b1v[q];
  if constexpr (OUTF16) {
    u32x4 pkd = {pk(o[0], o[1]), pk(o[2], o[3]), pk(o[4], o[5]), pk(o[6], o[7])};
    *(u32x4*)((u16*)out + (long)row * 512 + lane * 8) = pkd;
  } else {
    float* dst = (float*)out + (long)row * 512 + lane * 8;
    *(f32x4*)dst = (f32x4){o[0], o[1], o[2], o[3]};
    *(f32x4*)(dst + 4) = (f32x4){o[4], o[5], o[6], o[7]};
  }
}

// ---------- launch ----------
extern "C" void kernel_launch(void* const* d_in, const int* in_sizes, int n_in,
                              void* d_out, int out_size, void* d_ws, size_t ws_size,
                              hipStream_t stream) {
  const float* x = (const float*)d_in[0];
  const float* wp = (const float*)d_in[1];
  const float* w1 = (const float*)d_in[2];
  const float* b1 = (const float*)d_in[3];
  const float* w2 = (const float*)d_in[4];
  const float* b2 = (const float*)d_in[5];
  const float* g1 = (const float*)d_in[6];
  const float* be1 = (const float*)d_in[7];
  const float* g2 = (const float*)d_in[8];
  const float* be2 = (const float*)d_in[9];

  char* ws = (char*)d_ws;
  size_t off = 0;
  auto alloc = [&](size_t bytes) {
    char* p = ws + off;
    off += (bytes + 255) & ~(size_t)255;
    return p;
  };
  u16* wpb = (u16*)alloc(2560 * 1024 * 2);      // in_proj f16
  u16* w1b = (u16*)alloc(2048 * 512 * 2);       // w1 f16
  u16* w2b = (u16*)alloc(512 * 2048 * 2);       // w2 f16
  char* xb_region = alloc(33554432);            // x f16 -> attn_out f16
  u16* qk = (u16*)alloc(67108864);              // [q|k] f16 -> attnw -> ff1
  u16* vT = (u16*)alloc(16777216);              // v transposed (B,512,2048) f16
  u16* hb = (u16*)alloc(16777216);              // h f16
  // scores: all 8 batches in one region if ws allows, else 2 rounds of 4
  int bpl = (ws_size >= off + (size_t)67108864) ? 8 : 4;
  char* sc_region = alloc((size_t)bpl * 2048 * 2048 * 2);
  if (off > ws_size) return;  // workspace too small -> visible failure

  u16* xb = (u16*)xb_region;
  u16* attn16 = (u16*)xb_region;                // PV output f16 (x dead by then)
  u16* scores = (u16*)sc_region;                // f16 scores
  u16* y16 = (u16*)sc_region;                   // ff2 f16 out (scores dead)
  u16* ff1 = qk;

  const float SC = (float)(0.03125 * 2.0 * 7.6246189861593985);  // sqrt(1/E)*2*ln(2048)

  cvt_all<<<dim3(10496), dim3(256), 0, stream>>>(x, xb, wp, wpb, w1, w1b, w2, w2b);

  {  // proj: (16384x1024) @ (2560x1024)^T, split epilogue
    GemmP p{};
    p.A = xb; p.lda = 1024; p.B = wpb; p.ldb = 1024; p.K = 1024;
    p.qk = qk; p.vT = vT; p.scale = SC;
    gemm_bt<1><<<dim3(20, 128, 1), 256, 0, stream>>>(p);
  }

  for (int it = 0; it < 8 / bpl; ++it) {  // scores + softmax
    int b0 = it * bpl;
    GemmP p{};
    p.A = qk + (long)b0 * 4194304; p.lda = 1024; p.bsA = 4194304;
    p.B = qk + (long)b0 * 4194304 + 2097152; p.ldb = 1024; p.bsB = 4194304;
    p.K = 1024; p.Cb = scores; p.ldc = 2048; p.bsC = 4194304;
    gemm_bt<4><<<dim3(16, 16, bpl), 256, 0, stream>>>(p);
    softmax_rows<<<dim3(bpl * 2048), dim3(256), 0, stream>>>(scores, qk, b0);
  }

  {  // PV: attnw(2048x2048) @ vT(512x2048)^T per batch -> f16
    GemmP p{};
    p.A = qk; p.lda = 2048; p.bsA = 4194304;
    p.B = vT; p.ldb = 2048; p.bsB = 1048576;
    p.K = 2048; p.Cb = attn16; p.ldc = 512; p.bsC = 1048576;
    gemm_bt<4><<<dim3(4, 16, 8), 256, 0, stream>>>(p);
  }

  ln_rows<1, 1><<<dim3(4096), dim3(256), 0, stream>>>(attn16, g1, be1, hb);

  {  // ff1: h(16384x512) @ w1(2048x512)^T, +b1 relu -> f16
    GemmP p{};
    p.A = hb; p.lda = 512; p.B = w1b; p.ldb = 512; p.K = 512;
    p.Cb = ff1; p.ldc = 2048; p.bias = b1;
    gemm_bt<2><<<dim3(16, 128, 1), 256, 0, stream>>>(p);
  }

  {  // ff2: ff1(16384x2048) @ w2(512x2048)^T, +b2 +h -> f16
    GemmP p{};
    p.A = ff1; p.lda = 2048; p.B = w2b; p.ldb = 2048; p.K = 2048;
    p.Cb = y16; p.bias = b2; p.resid = hb;
    gemm_bt<3><<<dim3(4, 128, 1), 256, 0, stream>>>(p);
  }

  ln_rows<1, 0><<<dim3(4096), dim3(256), 0, stream>>>(y16, g2, be2, (float*)d_out);
}

// Round 6
// 394.611 us; speedup vs baseline: 1.0853x; 1.0140x over previous
//
#include <hip/hip_runtime.h>
#include <hip/hip_bf16.h>

// ---------- types ----------
typedef unsigned short u16;
typedef unsigned int u32;
typedef float f32x4 __attribute__((ext_vector_type(4)));
typedef _Float16 f16x8 __attribute__((ext_vector_type(8)));
typedef u32 u32x4 __attribute__((ext_vector_type(4)));
typedef u32 u32x2 __attribute__((ext_vector_type(2)));

#define SEQ 2048
#define EDIM 1024

__device__ __forceinline__ u16 f2h(float f) {
  _Float16 h = (_Float16)f;
  return __builtin_bit_cast(u16, h);
}
__device__ __forceinline__ float h2f(u16 u) {
  return (float)__builtin_bit_cast(_Float16, u);
}
__device__ __forceinline__ u32 pk(float a, float b) {
  return (u32)f2h(a) | ((u32)f2h(b) << 16);
}

// ---------- fused fp32 -> fp16 convert for all 4 inputs, 8 elems/thread ----
#define N_X  2097152
#define N_WP 327680
#define N_W1 131072
#define N_W2 131072
__global__ __launch_bounds__(256) void cvt_all(const float* __restrict__ x, u16* __restrict__ xb,
                                               const float* __restrict__ wp, u16* __restrict__ wpb,
                                               const float* __restrict__ w1, u16* __restrict__ w1b,
                                               const float* __restrict__ w2, u16* __restrict__ w2b) {
  int i = blockIdx.x * 256 + threadIdx.x;
  const float* src; u16* dst; int li;
  if (i < N_X) { src = x; dst = xb; li = i; }
  else if (i < N_X + N_WP) { src = wp; dst = wpb; li = i - N_X; }
  else if (i < N_X + N_WP + N_W1) { src = w1; dst = w1b; li = i - N_X - N_WP; }
  else if (i < N_X + N_WP + N_W1 + N_W2) { src = w2; dst = w2b; li = i - N_X - N_WP - N_W1; }
  else return;
  const f32x4* p = (const f32x4*)(src + (size_t)li * 8);
  f32x4 a = p[0], b = p[1];
  u32x4 o = {pk(a[0], a[1]), pk(a[2], a[3]), pk(b[0], b[1]), pk(b[2], b[3])};
  *(u32x4*)(dst + (size_t)li * 8) = o;
}

struct GemmP {
  const u16* A; const u16* B;
  int lda, ldb, K;
  long bsA, bsB, bsC;       // per-blockIdx.z element strides
  int ldc;
  u16* Cb;                  // EPI 2/3/4 (f16 store)
  const float* bias;        // EPI 2,3
  const u16* resid;         // EPI 3 (h, f16, ld 512)
  u16* qk; u16* vT;         // EPI 1 (proj split)
  float scale;              // EPI 1
};

// =======================================================================
// 256x256 tile, BK=32, 4 LDS slots (128KB), 8 waves (2Mx4N, 128x64/wave).
// READ-SKEWED pipeline: each phase issues NEXT phase's 12 ds_read_b128
// into the alternate register set + 4 global_load_lds for slot p+3, then
// runs 32 MFMA on the PREVIOUS set. Counted lgkm waits come from the
// compiler (12 newer reads outstanding); vmcnt(4) counted, never 0 in
// steady state; raw s_barrier (no drain). Bank layout identical to the
// measured-0-conflict round-2 kernel.
// EPI: 1 = proj split, 2 = +bias relu f16 (ff1), 4 = plain f16 (scores).
// =======================================================================
template <int EPI>
__global__ __launch_bounds__(512, 2) void gemm256(GemmP p) {
  __shared__ __align__(16) char lds[131072];
  const int tid = threadIdx.x;
  const int lane = tid & 63;
  const int wave = tid >> 6;
  const int wm = wave >> 2, wn = wave & 3;     // 2 x 4 waves
  const int bn0 = blockIdx.x * 256;
  const int bm0 = blockIdx.y * 256;
  const int z = blockIdx.z;
  const u16* Ab = p.A + (long)z * p.bsA + (long)bm0 * p.lda;
  const u16* Bb = p.B + (long)z * p.bsB + (long)bn0 * p.ldb;

  // staging: per slot, A = 256 rows x 4 slots(16B) = 1024 chunks; B same.
  const int ch0 = tid, ch1 = tid + 512;
  const int r0 = ch0 >> 2, s0 = ch0 & 3;
  const int r1 = ch1 >> 2, s1 = ch1 & 3;
  const long srcA0 = (long)r0 * p.lda + ((s0 ^ ((r0 >> 1) & 3)) << 3);
  const long srcA1 = (long)r1 * p.lda + ((s1 ^ ((r1 >> 1) & 3)) << 3);
  const long srcB0 = (long)r0 * p.ldb + ((s0 ^ ((r0 >> 1) & 3)) << 3);
  const long srcB1 = (long)r1 * p.ldb + ((s1 ^ ((r1 >> 1) & 3)) << 3);

  auto stage = [&](int s) {
    const int base = (s & 3) * 32768;
    const int k0 = s * 32;
    __builtin_amdgcn_global_load_lds(
        (const __attribute__((address_space(1))) u32*)(Ab + k0 + srcA0),
        (__attribute__((address_space(3))) u32*)(lds + base + ch0 * 16), 16, 0, 0);
    __builtin_amdgcn_global_load_lds(
        (const __attribute__((address_space(1))) u32*)(Ab + k0 + srcA1),
        (__attribute__((address_space(3))) u32*)(lds + base + ch1 * 16), 16, 0, 0);
    __builtin_amdgcn_global_load_lds(
        (const __attribute__((address_space(1))) u32*)(Bb + k0 + srcB0),
        (__attribute__((address_space(3))) u32*)(lds + base + 16384 + ch0 * 16), 16, 0, 0);
    __builtin_amdgcn_global_load_lds(
        (const __attribute__((address_space(1))) u32*)(Bb + k0 + srcB1),
        (__attribute__((address_space(3))) u32*)(lds + base + 16384 + ch1 * 16), 16, 0, 0);
  };

  // ds_read offsets (slot-relative; measured conflict-free in rounds 2-5)
  int aoff[8], boff[4];
#pragma unroll
  for (int m = 0; m < 8; ++m) {
    int r = wm * 128 + m * 16 + (lane & 15);
    aoff[m] = r * 64 + ((((lane >> 4)) ^ ((r >> 1) & 3)) << 4);
  }
#pragma unroll
  for (int n = 0; n < 4; ++n) {
    int r = wn * 64 + n * 16 + (lane & 15);
    boff[n] = 16384 + r * 64 + ((((lane >> 4)) ^ ((r >> 1) & 3)) << 4);
  }

  f32x4 acc[8][4] = {};
  f16x8 avc[8], bvc[4], avn[8], bvn[4];

  // prologue: stage slots 0..2; all-waves stage(0) landed; read R(0)
  stage(0); stage(1); stage(2);
  asm volatile("s_waitcnt vmcnt(8)" ::: "memory");
  __builtin_amdgcn_s_barrier();
  {
    const char* b0 = lds;
#pragma unroll
    for (int m = 0; m < 8; ++m) avc[m] = *(const f16x8*)(b0 + aoff[m]);
#pragma unroll
    for (int n = 0; n < 4; ++n) bvc[n] = *(const f16x8*)(b0 + boff[n]);
  }

  const int NS = p.K >> 5;  // NS even (K multiple of 64), NS >= 16
  for (int s = 0; s < NS; s += 2) {
    // ------- even phase: MFMA on avc/bvc; prefetch R(s+1) into avn/bvn ----
    asm volatile("s_waitcnt vmcnt(4)" ::: "memory");  // stage(s+1) landed (own)
    __builtin_amdgcn_s_barrier();                     // => landed for ALL waves
    {
      const char* bn = lds + ((s + 1) & 3) * 32768;
#pragma unroll
      for (int m = 0; m < 8; ++m) avn[m] = *(const f16x8*)(bn + aoff[m]);
#pragma unroll
      for (int n = 0; n < 4; ++n) bvn[n] = *(const f16x8*)(bn + boff[n]);
      if (s + 3 < NS) stage(s + 3);
    }
    __builtin_amdgcn_sched_barrier(0);  // keep read/stage issue above MFMA
    __builtin_amdgcn_s_setprio(1);
#pragma unroll
    for (int m = 0; m < 8; ++m)
#pragma unroll
      for (int n = 0; n < 4; ++n)
        acc[m][n] = __builtin_amdgcn_mfma_f32_16x16x32_f16(avc[m], bvc[n], acc[m][n], 0, 0, 0);
    __builtin_amdgcn_s_setprio(0);

    // ------- odd phase: MFMA on avn/bvn; prefetch R(s+2) into avc/bvc -----
    asm volatile("s_waitcnt vmcnt(4)" ::: "memory");  // stage(s+2) landed (own)
    __builtin_amdgcn_s_barrier();
    {
      if (s + 2 < NS) {
        const char* bn2 = lds + ((s + 2) & 3) * 32768;
#pragma unroll
        for (int m = 0; m < 8; ++m) avc[m] = *(const f16x8*)(bn2 + aoff[m]);
#pragma unroll
        for (int n = 0; n < 4; ++n) bvc[n] = *(const f16x8*)(bn2 + boff[n]);
      }
      if (s + 4 < NS) stage(s + 4);
    }
    __builtin_amdgcn_sched_barrier(0);
    __builtin_amdgcn_s_setprio(1);
#pragma unroll
    for (int m = 0; m < 8; ++m)
#pragma unroll
      for (int n = 0; n < 4; ++n)
        acc[m][n] = __builtin_amdgcn_mfma_f32_16x16x32_f16(avn[m], bvn[n], acc[m][n], 0, 0, 0);
    __builtin_amdgcn_s_setprio(0);
  }

  // epilogue: C row = (lane>>4)*4+reg, col = lane&15
#pragma unroll
  for (int i = 0; i < 8; ++i) {
#pragma unroll
    for (int j = 0; j < 4; ++j) {
      int mb = bm0 + wm * 128 + i * 16 + ((lane >> 4) << 2);
      int n = bn0 + wn * 64 + j * 16 + (lane & 15);
      if constexpr (EPI == 1) {  // proj split into q*SCALE | k | vT
        int b = mb >> 11, l0 = mb & 2047;
        if (n < EDIM) {
          u16* dst = p.qk + (long)b * 4194304 + (long)l0 * 1024 + n;
#pragma unroll
          for (int r = 0; r < 4; ++r) dst[r * 1024] = f2h(acc[i][j][r] * p.scale);
        } else if (n < 2 * EDIM) {
          u16* dst = p.qk + (long)b * 4194304 + 2097152 + (long)l0 * 1024 + (n - EDIM);
#pragma unroll
          for (int r = 0; r < 4; ++r) dst[r * 1024] = f2h(acc[i][j][r]);
        } else {  // vT[b][n-2048][l0..l0+3]
          u16* dst = p.vT + (long)b * 1048576 + (long)(n - 2 * EDIM) * 2048 + l0;
          u32x2 w = {pk(acc[i][j][0], acc[i][j][1]), pk(acc[i][j][2], acc[i][j][3])};
          *(u32x2*)dst = w;
        }
      } else if constexpr (EPI == 2) {  // +bias, relu, f16 out (ff1)
        u16* dst = p.Cb + (long)mb * p.ldc + n;
        float bias = p.bias[n];
#pragma unroll
        for (int r = 0; r < 4; ++r) dst[(long)r * p.ldc] = f2h(fmaxf(acc[i][j][r] + bias, 0.f));
      } else {  // EPI 4: plain f16 (scores)
        u16* dst = p.Cb + (long)z * p.bsC + (long)mb * p.ldc + n;
#pragma unroll
        for (int r = 0; r < 4; ++r) dst[(long)r * p.ldc] = f2h(acc[i][j][r]);
      }
    }
  }
}

// =======================================================================
// 128x128 tile 2-barrier kernel (proven) — PV / ff2 (N=512 shapes).
// =======================================================================
template <int EPI>
__global__ __launch_bounds__(256) void gemm_bt(GemmP p) {
  __shared__ __align__(16) char lds[32768];
  const int tid = threadIdx.x;
  const int lane = tid & 63;
  const int wave = tid >> 6;
  const int wm = wave >> 1, wn = wave & 1;
  const int bn0 = blockIdx.x * 128;
  const int bm0 = blockIdx.y * 128;
  const int z = blockIdx.z;

  const u16* gA[4]; const u16* gB[4];
  int ldsA[4], ldsB[4];
  {
    const u16* Ab = p.A + (long)z * p.bsA + (long)bm0 * p.lda;
    const u16* Bb = p.B + (long)z * p.bsB + (long)bn0 * p.ldb;
#pragma unroll
    for (int i = 0; i < 4; ++i) {
      int ch = i * 256 + tid;
      int row = ch >> 3, s = ch & 7;
      int ks = ((s ^ (row & 7)) << 3);
      gA[i] = Ab + (long)row * p.lda + ks;
      gB[i] = Bb + (long)row * p.ldb + ks;
      ldsA[i] = ch * 16;
      ldsB[i] = 16384 + ch * 16;
    }
  }
  auto stage = [&]() {
#pragma unroll
    for (int i = 0; i < 4; ++i) {
      __builtin_amdgcn_global_load_lds(
          (const __attribute__((address_space(1))) u32*)gA[i],
          (__attribute__((address_space(3))) u32*)(lds + ldsA[i]), 16, 0, 0);
      gA[i] += 64;
    }
#pragma unroll
    for (int i = 0; i < 4; ++i) {
      __builtin_amdgcn_global_load_lds(
          (const __attribute__((address_space(1))) u32*)gB[i],
          (__attribute__((address_space(3))) u32*)(lds + ldsB[i]), 16, 0, 0);
      gB[i] += 64;
    }
  };

  int ao[2][4], bo[2][4];
#pragma unroll
  for (int h = 0; h < 2; ++h) {
#pragma unroll
    for (int i = 0; i < 4; ++i) {
      int rA = wm * 64 + i * 16 + (lane & 15);
      ao[h][i] = rA * 128 + ((((h << 2) | (lane >> 4)) ^ (rA & 7)) << 4);
      int rB = wn * 64 + i * 16 + (lane & 15);
      bo[h][i] = 16384 + rB * 128 + ((((h << 2) | (lane >> 4)) ^ (rB & 7)) << 4);
    }
  }

  f32x4 acc[4][4] = {};
  stage();
  const int nk = p.K >> 6;
  for (int kt = 0; kt < nk; ++kt) {
    __syncthreads();
#pragma unroll
    for (int h = 0; h < 2; ++h) {
      f16x8 av[4], bv[4];
#pragma unroll
      for (int i = 0; i < 4; ++i) av[i] = *(const f16x8*)(lds + ao[h][i]);
#pragma unroll
      for (int j = 0; j < 4; ++j) bv[j] = *(const f16x8*)(lds + bo[h][j]);
#pragma unroll
      for (int i = 0; i < 4; ++i)
#pragma unroll
        for (int j = 0; j < 4; ++j)
          acc[i][j] = __builtin_amdgcn_mfma_f32_16x16x32_f16(av[i], bv[j], acc[i][j], 0, 0, 0);
    }
    __syncthreads();
    if (kt + 1 < nk) stage();
  }

#pragma unroll
  for (int i = 0; i < 4; ++i) {
#pragma unroll
    for (int j = 0; j < 4; ++j) {
      int mb = bm0 + wm * 64 + i * 16 + ((lane >> 4) << 2);
      int n = bn0 + wn * 64 + j * 16 + (lane & 15);
      if constexpr (EPI == 3) {  // +bias +resid, f16 out (ff2), ld 512
        float bias = p.bias[n];
        u16* dst = p.Cb + (long)mb * 512 + n;
        const u16* rs = p.resid + (long)mb * 512 + n;
#pragma unroll
        for (int r = 0; r < 4; ++r) dst[r * 512] = f2h(acc[i][j][r] + bias + h2f(rs[r * 512]));
      } else {  // EPI 4: plain f16 (PV)
        u16* dst = p.Cb + (long)z * p.bsC + (long)mb * p.ldc + n;
#pragma unroll
        for (int r = 0; r < 4; ++r) dst[(long)r * p.ldc] = f2h(acc[i][j][r]);
      }
    }
  }
}

// ---------- row softmax: 1 block / row of 2048 f16 -> f16 weights ----------
__global__ __launch_bounds__(256) void softmax_rows(const u16* __restrict__ S,
                                                    u16* __restrict__ W, int b0) {
  int r = blockIdx.x;
  int z = r >> 11, l = r & 2047;
  int tid = threadIdx.x, lane = tid & 63, wv = tid >> 6;
  const u16* x = S + (long)r * 2048 + tid * 8;
  u32x4 raw = *(const u32x4*)x;
  float e[8];
#pragma unroll
  for (int q = 0; q < 4; ++q) {
    e[2 * q] = h2f((u16)(raw[q] & 0xffff));
    e[2 * q + 1] = h2f((u16)(raw[q] >> 16));
  }
  float m = e[0];
#pragma unroll
  for (int q = 1; q < 8; ++q) m = fmaxf(m, e[q]);
#pragma unroll
  for (int off = 32; off; off >>= 1) m = fmaxf(m, __shfl_xor(m, off));
  __shared__ float red[8];
  if (lane == 0) red[wv] = m;
  __syncthreads();
  m = fmaxf(fmaxf(red[0], red[1]), fmaxf(red[2], red[3]));
  float s = 0.f;
#pragma unroll
  for (int q = 0; q < 8; ++q) { e[q] = __expf(e[q] - m); s += e[q]; }
#pragma unroll
  for (int off = 32; off; off >>= 1) s += __shfl_xor(s, off);
  if (lane == 0) red[4 + wv] = s;
  __syncthreads();
  s = red[4] + red[5] + red[6] + red[7];
  float inv = 1.f / s;
  u32x4 o = {pk(e[0] * inv, e[1] * inv), pk(e[2] * inv, e[3] * inv),
             pk(e[4] * inv, e[5] * inv), pk(e[6] * inv, e[7] * inv)};
  *(u32x4*)(W + (long)(b0 + z) * 4194304 + (long)l * 2048 + tid * 8) = o;
}

// ---------- LayerNorm over 512, wave per row ----------
template <int INF16, int OUTF16>
__global__ __launch_bounds__(256) void ln_rows(const void* __restrict__ X,
                                               const float* __restrict__ g,
                                               const float* __restrict__ bb,
                                               void* __restrict__ out) {
  int row = blockIdx.x * 4 + (threadIdx.x >> 6);
  int lane = threadIdx.x & 63;
  float v[8];
  if constexpr (INF16) {
    u32x4 raw = *(const u32x4*)((const u16*)X + (long)row * 512 + lane * 8);
#pragma unroll
    for (int q = 0; q < 4; ++q) {
      v[2 * q] = h2f((u16)(raw[q] & 0xffff));
      v[2 * q + 1] = h2f((u16)(raw[q] >> 16));
    }
  } else {
    const float* x = (const float*)X + (long)row * 512 + lane * 8;
    f32x4 a = *(const f32x4*)x, b = *(const f32x4*)(x + 4);
#pragma unroll
    for (int q = 0; q < 4; ++q) { v[q] = a[q]; v[4 + q] = b[q]; }
  }
  float s = 0.f, sq = 0.f;
#pragma unroll
  for (int q = 0; q < 8; ++q) { s += v[q]; sq += v[q] * v[q]; }
#pragma unroll
  for (int off = 32; off; off >>= 1) {
    s += __shfl_xor(s, off);
    sq += __shfl_xor(sq, off);
  }
  float mean = s * (1.f / 512.f);
  float var = sq * (1.f / 512.f) - mean * mean;
  float rstd = rsqrtf(var + 1e-5f);
  f32x4 g0 = *(const f32x4*)(g + lane * 8), g1v = *(const f32x4*)(g + lane * 8 + 4);
  f32x4 b0 = *(const f32x4*)(bb + lane * 8), b1v = *(const f32x4*)(bb + lane * 8 + 4);
  float o[8];
#pragma unroll
  for (int q = 0; q < 4; ++q) o[q] = (v[q] - mean) * rstd * g0[q] + b0[q];
#pragma unroll
  for (int q = 0; q < 4; ++q) o[4 + q] = (v[4 + q] - mean) * rstd * g1v[q] + b1v[q];
  if constexpr (OUTF16) {
    u32x4 pkd = {pk(o[0], o[1]), pk(o[2], o[3]), pk(o[4], o[5]), pk(o[6], o[7])};
    *(u32x4*)((u16*)out + (long)row * 512 + lane * 8) = pkd;
  } else {
    float* dst = (float*)out + (long)row * 512 + lane * 8;
    *(f32x4*)dst = (f32x4){o[0], o[1], o[2], o[3]};
    *(f32x4*)(dst + 4) = (f32x4){o[4], o[5], o[6], o[7]};
  }
}

// ---------- launch ----------
extern "C" void kernel_launch(void* const* d_in, const int* in_sizes, int n_in,
                              void* d_out, int out_size, void* d_ws, size_t ws_size,
                              hipStream_t stream) {
  const float* x = (const float*)d_in[0];
  const float* wp = (const float*)d_in[1];
  const float* w1 = (const float*)d_in[2];
  const float* b1 = (const float*)d_in[3];
  const float* w2 = (const float*)d_in[4];
  const float* b2 = (const float*)d_in[5];
  const float* g1 = (const float*)d_in[6];
  const float* be1 = (const float*)d_in[7];
  const float* g2 = (const float*)d_in[8];
  const float* be2 = (const float*)d_in[9];

  char* ws = (char*)d_ws;
  size_t off = 0;
  auto alloc = [&](size_t bytes) {
    char* p = ws + off;
    off += (bytes + 255) & ~(size_t)255;
    return p;
  };
  u16* wpb = (u16*)alloc(2560 * 1024 * 2);
  u16* w1b = (u16*)alloc(2048 * 512 * 2);
  u16* w2b = (u16*)alloc(512 * 2048 * 2);
  char* xb_region = alloc(33554432);            // x f16 -> attn_out f16
  u16* qk = (u16*)alloc(67108864);              // [q|k] f16 -> attnw -> ff1
  u16* vT = (u16*)alloc(16777216);              // v transposed f16
  u16* hb = (u16*)alloc(16777216);              // h f16
  int bpl = (ws_size >= off + (size_t)67108864) ? 8 : 4;
  char* sc_region = alloc((size_t)bpl * 2048 * 2048 * 2);
  if (off > ws_size) return;

  u16* xb = (u16*)xb_region;
  u16* attn16 = (u16*)xb_region;
  u16* scores = (u16*)sc_region;
  u16* y16 = (u16*)sc_region;
  u16* ff1 = qk;

  const float SC = (float)(0.03125 * 2.0 * 7.6246189861593985);

  cvt_all<<<dim3(10496), dim3(256), 0, stream>>>(x, xb, wp, wpb, w1, w1b, w2, w2b);

  {  // proj: (16384x1024) @ (2560x1024)^T, split epilogue
    GemmP p{};
    p.A = xb; p.lda = 1024; p.B = wpb; p.ldb = 1024; p.K = 1024;
    p.qk = qk; p.vT = vT; p.scale = SC;
    gemm256<1><<<dim3(10, 64, 1), 512, 0, stream>>>(p);
  }

  for (int it = 0; it < 8 / bpl; ++it) {  // scores + softmax
    int b0 = it * bpl;
    GemmP p{};
    p.A = qk + (long)b0 * 4194304; p.lda = 1024; p.bsA = 4194304;
    p.B = qk + (long)b0 * 4194304 + 2097152; p.ldb = 1024; p.bsB = 4194304;
    p.K = 1024; p.Cb = scores; p.ldc = 2048; p.bsC = 4194304;
    gemm256<4><<<dim3(8, 8, bpl), 512, 0, stream>>>(p);
    softmax_rows<<<dim3(bpl * 2048), dim3(256), 0, stream>>>(scores, qk, b0);
  }

  {  // PV: attnw(2048x2048) @ vT(512x2048)^T per batch -> f16
    GemmP p{};
    p.A = qk; p.lda = 2048; p.bsA = 4194304;
    p.B = vT; p.ldb = 2048; p.bsB = 1048576;
    p.K = 2048; p.Cb = attn16; p.ldc = 512; p.bsC = 1048576;
    gemm_bt<4><<<dim3(4, 16, 8), 256, 0, stream>>>(p);
  }

  ln_rows<1, 1><<<dim3(4096), dim3(256), 0, stream>>>(attn16, g1, be1, hb);

  {  // ff1: h(16384x512) @ w1(2048x512)^T, +b1 relu -> f16
    GemmP p{};
    p.A = hb; p.lda = 512; p.B = w1b; p.ldb = 512; p.K = 512;
    p.Cb = ff1; p.ldc = 2048; p.bias = b1;
    gemm256<2><<<dim3(8, 64, 1), 512, 0, stream>>>(p);
  }

  {  // ff2: ff1(16384x2048) @ w2(512x2048)^T, +b2 +h -> f16
    GemmP p{};
    p.A = ff1; p.lda = 2048; p.B = w2b; p.ldb = 2048; p.K = 2048;
    p.Cb = y16; p.bias = b2; p.resid = hb;
    gemm_bt<3><<<dim3(4, 128, 1), 256, 0, stream>>>(p);
  }

  ln_rows<1, 0><<<dim3(4096), dim3(256), 0, stream>>>(y16, g2, be2, (float*)d_out);
}